// Round 1
// baseline (1175.470 us; speedup 1.0000x reference)
//
#include <hip/hip_runtime.h>

#define DD 64

// One wave (64 lanes) per edge: lane d handles feature d.
// Coalesced 256B gather of x[src], 64 fp32 atomics into sum[dst].
__global__ __launch_bounds__(256)
void scatter_kernel(const float* __restrict__ xin,
                    const int* __restrict__ src,
                    const int* __restrict__ dst,
                    float* __restrict__ sums,
                    float* __restrict__ deg,
                    int nE, int addDeg)
{
    int lane = threadIdx.x & 63;
    int waveInBlock = threadIdx.x >> 6;
    long wave0 = (long)blockIdx.x * 4 + waveInBlock;
    long totWaves = (long)gridDim.x * 4;
    for (long e = wave0; e < nE; e += totWaves) {
        int s = src[e];
        int d = dst[e];
        float v = xin[(size_t)s * DD + lane];
        atomicAdd(&sums[(size_t)d * DD + lane], v);
        if (addDeg && lane == 0) atomicAdd(&deg[d], 1.0f);
    }
}

// out[node][lane] = (1/max(deg,1)) * dot(aggr_row, Wl_row[lane]) + bl[lane]
//                 + dot(x_row, Wr_row[lane])
// Each lane keeps its W columns (= rows of Wl/Wr, since out = in @ W.T) in
// 128 VGPRs; node rows come in as wave-uniform float4 broadcast loads.
__global__ __launch_bounds__(256)
void dense_kernel(const float* __restrict__ aggr,
                  const float* __restrict__ deg,
                  const float* __restrict__ xin,
                  const float* __restrict__ Wl,
                  const float* __restrict__ bl,
                  const float* __restrict__ Wr,
                  float* __restrict__ out,
                  int nN)
{
    int lane = threadIdx.x & 63;
    int waveInBlock = threadIdx.x >> 6;
    float wl[DD], wr[DD];
#pragma unroll
    for (int k = 0; k < DD; k += 4) {
        *(float4*)&wl[k] = *(const float4*)&Wl[lane * DD + k];
        *(float4*)&wr[k] = *(const float4*)&Wr[lane * DD + k];
    }
    float bias = bl[lane];
    int totWaves = gridDim.x * 4;
    for (int node = blockIdx.x * 4 + waveInBlock; node < nN; node += totWaves) {
        const float* arow = aggr + (size_t)node * DD;
        const float* xrow = xin + (size_t)node * DD;
        float accL = 0.f, accR = 0.f;
#pragma unroll
        for (int k = 0; k < DD; k += 4) {
            float4 av = *(const float4*)(arow + k);
            float4 xv = *(const float4*)(xrow + k);
            accL = fmaf(av.x, wl[k + 0], accL);
            accL = fmaf(av.y, wl[k + 1], accL);
            accL = fmaf(av.z, wl[k + 2], accL);
            accL = fmaf(av.w, wl[k + 3], accL);
            accR = fmaf(xv.x, wr[k + 0], accR);
            accR = fmaf(xv.y, wr[k + 1], accR);
            accR = fmaf(xv.z, wr[k + 2], accR);
            accR = fmaf(xv.w, wr[k + 3], accR);
        }
        float inv = 1.0f / fmaxf(deg[node], 1.0f);
        out[(size_t)node * DD + lane] = fmaf(accL, inv, bias) + accR;
    }
}

extern "C" void kernel_launch(void* const* d_in, const int* in_sizes, int n_in,
                              void* d_out, int out_size, void* d_ws, size_t ws_size,
                              hipStream_t stream)
{
    const float* x   = (const float*)d_in[0];
    const int*   ei  = (const int*)d_in[1];
    const float* W1l = (const float*)d_in[2];
    const float* b1l = (const float*)d_in[3];
    const float* W1r = (const float*)d_in[4];
    const float* W2l = (const float*)d_in[5];
    const float* b2l = (const float*)d_in[6];
    const float* W2r = (const float*)d_in[7];
    float* out = (float*)d_out;

    int nN = in_sizes[0] / DD;   // 100000
    int nE = in_sizes[1] / 2;    // 1600000
    const int* src = ei;
    const int* dst = ei + nE;

    // ws layout (floats): deg[nN] | sums[nN*DD] | x1[nN*DD]  (~51.6 MB)
    float* deg  = (float*)d_ws;
    float* sums = deg + nN;
    float* x1   = sums + (size_t)nN * DD;

    // zero deg + sums (contiguous)
    hipMemsetAsync(deg, 0, sizeof(float) * ((size_t)nN * (DD + 1)), stream);

    const int sblocks = 32768;  // grid-stride over 1.6M edge-waves
    const int dblocks = 1024;   // grid-stride over 100k node-waves

    // Layer 1
    scatter_kernel<<<sblocks, 256, 0, stream>>>(x, src, dst, sums, deg, nE, 1);
    dense_kernel<<<dblocks, 256, 0, stream>>>(sums, deg, x, W1l, b1l, W1r, x1, nN);

    // Layer 2 (deg unchanged; re-zero sums)
    hipMemsetAsync(sums, 0, sizeof(float) * (size_t)nN * DD, stream);
    scatter_kernel<<<sblocks, 256, 0, stream>>>(x1, src, dst, sums, deg, nE, 0);
    dense_kernel<<<dblocks, 256, 0, stream>>>(sums, deg, x1, W2l, b2l, W2r, out, nN);
}

// Round 2
// 751.272 us; speedup vs baseline: 1.5646x; 1.5646x over previous
//
#include <hip/hip_runtime.h>

#define DD 64
#define SCAN_T 1024

// ---------- CSR build ----------

__global__ __launch_bounds__(256)
void hist_kernel(const int* __restrict__ dst, int* __restrict__ degi, int nE)
{
    for (int e = blockIdx.x * blockDim.x + threadIdx.x; e < nE;
         e += gridDim.x * blockDim.x)
        atomicAdd(&degi[dst[e]], 1);
}

// Block-local exclusive scan (Hillis-Steele) -> rs (local), block totals -> partials
__global__ __launch_bounds__(SCAN_T)
void scan1_kernel(const int* __restrict__ degi, int* __restrict__ rs,
                  int* __restrict__ partials, int nN)
{
    __shared__ int s[SCAN_T];
    int tid = threadIdx.x;
    int gid = blockIdx.x * SCAN_T + tid;
    int v = (gid < nN) ? degi[gid] : 0;
    s[tid] = v;
    __syncthreads();
    for (int off = 1; off < SCAN_T; off <<= 1) {
        int t = (tid >= off) ? s[tid - off] : 0;
        __syncthreads();
        s[tid] += t;
        __syncthreads();
    }
    if (gid < nN) rs[gid] = s[tid] - v;   // exclusive
    if (tid == SCAN_T - 1) partials[blockIdx.x] = s[SCAN_T - 1];
}

// Serial exclusive scan over block partials (<=128 entries) + grand total -> rs[nN]
__global__ void scan2_kernel(int* __restrict__ partials, int* __restrict__ rs,
                             int nblk, int nN)
{
    if (threadIdx.x == 0 && blockIdx.x == 0) {
        int running = 0;
        for (int b = 0; b < nblk; ++b) {
            int t = partials[b];
            partials[b] = running;
            running += t;
        }
        rs[nN] = running;   // == nE
    }
}

__global__ __launch_bounds__(SCAN_T)
void scan3_kernel(int* __restrict__ rs, const int* __restrict__ partials, int nN)
{
    int gid = blockIdx.x * SCAN_T + threadIdx.x;
    if (gid < nN) rs[gid] += partials[blockIdx.x];
}

__global__ __launch_bounds__(256)
void fill_kernel(const int* __restrict__ src, const int* __restrict__ dst,
                 const int* __restrict__ rs, int* __restrict__ cursor,
                 int* __restrict__ csr, int nE)
{
    for (int e = blockIdx.x * blockDim.x + threadIdx.x; e < nE;
         e += gridDim.x * blockDim.x) {
        int d = dst[e];
        int p = atomicAdd(&cursor[d], 1);
        csr[rs[d] + p] = src[e];
    }
}

// ---------- fused SAGE layer: mean-gather + dual dense ----------
// Wave per node, lane = feature dim. Gather neighbor rows (coalesced 256B),
// mean, then out[d'] = dot(aggr, Wl[d']) + bl[d'] + dot(x, Wr[d']) via __shfl
// broadcast against per-lane weight rows held in VGPRs.
__global__ __launch_bounds__(256)
void sage_fused(const float* __restrict__ xin,
                const int* __restrict__ csr,
                const int* __restrict__ rs,
                const float* __restrict__ Wl,
                const float* __restrict__ bl,
                const float* __restrict__ Wr,
                float* __restrict__ out, int nN)
{
    int lane = threadIdx.x & 63;
    int w = threadIdx.x >> 6;
    float wl[DD], wr[DD];
#pragma unroll
    for (int k = 0; k < DD; k += 4) {
        *(float4*)&wl[k] = *(const float4*)&Wl[lane * DD + k];
        *(float4*)&wr[k] = *(const float4*)&Wr[lane * DD + k];
    }
    float bias = bl[lane];
    int totWaves = gridDim.x * 4;
    for (int node = blockIdx.x * 4 + w; node < nN; node += totWaves) {
        int beg = rs[node], end = rs[node + 1];
        float a0 = 0.f, a1 = 0.f, a2 = 0.f, a3 = 0.f;
        int e = beg;
        for (; e + 4 <= end; e += 4) {
            int s0 = csr[e], s1 = csr[e + 1], s2 = csr[e + 2], s3 = csr[e + 3];
            a0 += xin[(size_t)s0 * DD + lane];
            a1 += xin[(size_t)s1 * DD + lane];
            a2 += xin[(size_t)s2 * DD + lane];
            a3 += xin[(size_t)s3 * DD + lane];
        }
        for (; e < end; ++e) a0 += xin[(size_t)csr[e] * DD + lane];
        float acc = (a0 + a1) + (a2 + a3);
        int deg = end - beg;
        float aggr = acc / (float)(deg > 0 ? deg : 1);
        float xv = xin[(size_t)node * DD + lane];

        float L0 = 0.f, L1 = 0.f, R0 = 0.f, R1 = 0.f;
#pragma unroll
        for (int k = 0; k < DD; k += 2) {
            float ak0 = __shfl(aggr, k);
            float xk0 = __shfl(xv, k);
            float ak1 = __shfl(aggr, k + 1);
            float xk1 = __shfl(xv, k + 1);
            L0 = fmaf(ak0, wl[k], L0);
            R0 = fmaf(xk0, wr[k], R0);
            L1 = fmaf(ak1, wl[k + 1], L1);
            R1 = fmaf(xk1, wr[k + 1], R1);
        }
        out[(size_t)node * DD + lane] = ((L0 + L1) + bias) + (R0 + R1);
    }
}

extern "C" void kernel_launch(void* const* d_in, const int* in_sizes, int n_in,
                              void* d_out, int out_size, void* d_ws, size_t ws_size,
                              hipStream_t stream)
{
    const float* x   = (const float*)d_in[0];
    const int*   ei  = (const int*)d_in[1];
    const float* W1l = (const float*)d_in[2];
    const float* b1l = (const float*)d_in[3];
    const float* W1r = (const float*)d_in[4];
    const float* W2l = (const float*)d_in[5];
    const float* b2l = (const float*)d_in[6];
    const float* W2r = (const float*)d_in[7];
    float* out = (float*)d_out;

    int nN = in_sizes[0] / DD;   // 100000
    int nE = in_sizes[1] / 2;    // 1600000
    const int* src = ei;
    const int* dst = ei + nE;

    // ws layout: degi[nN] | rs[nN+1] | partials[128] | csr[nE] | pad | x1[nN*DD]
    int* degi     = (int*)d_ws;
    int* rs       = degi + nN;
    int* partials = rs + nN + 1;
    int* csr      = partials + 128;
    size_t ofs = (size_t)(nN + nN + 1 + 128 + nE);
    ofs = (ofs + 3) & ~(size_t)3;            // 16B align
    float* x1 = (float*)d_ws + ofs;

    int nblk = (nN + SCAN_T - 1) / SCAN_T;   // 98

    // 1) degree histogram (int atomics)
    hipMemsetAsync(degi, 0, sizeof(int) * (size_t)nN, stream);
    hist_kernel<<<2048, 256, 0, stream>>>(dst, degi, nE);
    // 2) exclusive scan -> row_start
    scan1_kernel<<<nblk, SCAN_T, 0, stream>>>(degi, rs, partials, nN);
    scan2_kernel<<<1, 64, 0, stream>>>(partials, rs, nblk, nN);
    scan3_kernel<<<nblk, SCAN_T, 0, stream>>>(rs, partials, nN);
    // 3) fill CSR (degi reused as cursor)
    hipMemsetAsync(degi, 0, sizeof(int) * (size_t)nN, stream);
    fill_kernel<<<2048, 256, 0, stream>>>(src, dst, rs, degi, csr, nE);

    // 4) two fused SAGE layers (no atomics, gather-based)
    sage_fused<<<4096, 256, 0, stream>>>(x, csr, rs, W1l, b1l, W1r, x1, nN);
    sage_fused<<<4096, 256, 0, stream>>>(x1, csr, rs, W2l, b2l, W2r, out, nN);
}